// Round 1
// baseline (403.883 us; speedup 1.0000x reference)
//
#include <hip/hip_runtime.h>

// Conv2dSelfAttention: B=16, C=512, Cb=64, N=64*64=4096
// K0 W-prep: pack weights into MFMA fragment order (bf16 hi/lo) + bias concat
// K1 QKV: 192x64 block tile, 1024 blocks, 2-deep x prefetch, packed-A coalesced
//         loads, LDS-staged swizzled B fragments, split-bf16 MFMA
// K2a partial logits -> K2b wave-per-row reduce+softmax -> K2c M'=gamma*Wo@attn
// K3 out = M'@V + gamma*b_o + x

#define NB  16
#define NC  512
#define NCB 64
#define NSP 4096
#define NM  192

typedef __bf16 bf16x8 __attribute__((ext_vector_type(8)));
typedef unsigned short u16x8 __attribute__((ext_vector_type(8)));
typedef unsigned short u16x4 __attribute__((ext_vector_type(4)));
typedef float f32x4 __attribute__((ext_vector_type(4)));

union F8 { bf16x8 bf; u16x8 us; };

__device__ __forceinline__ unsigned short f2bfu(float f) {
  unsigned u = __builtin_bit_cast(unsigned, f);
  unsigned r = u + 0x7fffu + ((u >> 16) & 1u);   // RNE
  return (unsigned short)(r >> 16);
}
__device__ __forceinline__ float bfu2f(unsigned short h) {
  return __builtin_bit_cast(float, ((unsigned)h) << 16);
}

// ---------------- K0: pack weights to fragment order, bf16 hi/lo ----------------
// Packed layout: WhiP[((mt*16 + s)*64 + lane)*8 + j] where the value is
// W[row = mt*16 + (lane&15)][col = s*32 + (lane>>4)*8 + j].
// A-loads in K1 then read 64 lanes x 16B = 1KB CONTIGUOUS per instruction.
// hi: mt 0..11 (q,k,v rows 0..191); lo: mt 0..7 only (q,k).
__global__ __launch_bounds__(256) void k0_wprep(
    const float* __restrict__ wq, const float* __restrict__ wk,
    const float* __restrict__ wv,
    const float* __restrict__ bq, const float* __restrict__ bk,
    const float* __restrict__ bv,
    unsigned short* __restrict__ WhiP, unsigned short* __restrict__ WloP,
    float* __restrict__ biasAll) {
  int i = blockIdx.x * 256 + threadIdx.x;        // 0 .. 98303
  if (i < 12 * 16 * 64 * 8) {
    int j    = i & 7;
    int lane = (i >> 3) & 63;
    int s    = (i >> 9) & 15;
    int mt   = i >> 13;                          // 0..11
    int row = mt * 16 + (lane & 15);             // 0..191
    int col = s * 32 + (lane >> 4) * 8 + j;      // 0..511
    float f = (row < 64)  ? wq[row * NC + col]
            : (row < 128) ? wk[(row - 64) * NC + col]
                          : wv[(row - 128) * NC + col];
    unsigned short h = f2bfu(f);
    WhiP[i] = h;
    if (i < 8 * 16 * 64 * 8)                     // mt < 8 : q,k lo part
      WloP[i] = f2bfu(f - bfu2f(h));
  }
  if (i < 192) {
    biasAll[i] = (i < 64) ? bq[i] : (i < 128) ? bk[i - 64] : bv[i - 128];
  }
}

// ---------------- K1: QKV = Wqkv @ X_b ----------------
// Grid (64 nt, 16 b), 512 thr. Block tile 192m x 64n, K=512 in 16 steps of 32.
// Per wave (mh,nq): 4 qk m-tiles x3 split-MFMA + 2 v m-tiles x1 on ONE 16-col
// n-tile = 14 MFMA/step, acc = 6 f32x4 (24 regs -> 6+ waves/SIMD).
// Staging: thread (sn=t&63, skb=t>>6) loads 4 k-strided floats (n-coalesced
// 256B/wave-instr), converts hi/lo, writes one u16x4 to swizzled LDS slot.
// Double-buffered LDS, one barrier/step, TWO-step-deep register prefetch
// (xrA/xrB, loop manually unrolled x2 so all xr indexing is static).
// A fragments: packed order -> 1KB contiguous coalesced loads, L1-resident
// per-step working set (20KB shared by 8 waves x 4 blocks/CU).
#define K1_STEP(S, XR, BUF)                                                     \
  {                                                                             \
    union { u16x4 v; unsigned short a[4]; } hv, lv;                             \
    _Pragma("unroll")                                                           \
    for (int j = 0; j < 4; j++) {                                               \
      float f = XR[j];                                                          \
      unsigned short h = f2bfu(f);                                              \
      hv.a[j] = h;                                                              \
      lv.a[j] = f2bfu(f - bfu2f(h));                                            \
    }                                                                           \
    *(u16x4*)&ldsHi[BUF][sn][wslot] = hv.v;                                     \
    *(u16x4*)&ldsLo[BUF][sn][wslot] = lv.v;                                     \
    __syncthreads();                                                            \
    if ((S) < 14) {                                                             \
      const float* src = xb + (long)(((S) + 2) * 32 + skb * 4) * NSP;           \
      _Pragma("unroll")                                                         \
      for (int j = 0; j < 4; j++) XR[j] = src[(long)j * NSP];                   \
    }                                                                           \
    F8 bhi, blo;                                                                \
    bhi.us = *(const u16x8*)&ldsHi[BUF][nl][rslot];                             \
    blo.us = *(const u16x8*)&ldsLo[BUF][nl][rslot];                             \
    const unsigned short* ph = WhiP + ((long)(S) * 512 + (long)lane * 8);       \
    const unsigned short* pl = WloP + ((long)(S) * 512 + (long)lane * 8);       \
    _Pragma("unroll")                                                           \
    for (int i = 0; i < 4; i++) {                                               \
      const int mt = mh4 + i;                                                   \
      F8 Ahi, Alo;                                                              \
      Ahi.us = *(const u16x8*)&ph[(long)mt * 8192];                             \
      Alo.us = *(const u16x8*)&pl[(long)mt * 8192];                             \
      acc[i] = __builtin_amdgcn_mfma_f32_16x16x32_bf16(Ahi.bf, bhi.bf, acc[i], 0, 0, 0); \
      acc[i] = __builtin_amdgcn_mfma_f32_16x16x32_bf16(Ahi.bf, blo.bf, acc[i], 0, 0, 0); \
      acc[i] = __builtin_amdgcn_mfma_f32_16x16x32_bf16(Alo.bf, bhi.bf, acc[i], 0, 0, 0); \
    }                                                                           \
    _Pragma("unroll")                                                           \
    for (int i = 0; i < 2; i++) {                                               \
      const int mt = 8 + mh2 + i;                                               \
      F8 Ahi;                                                                   \
      Ahi.us = *(const u16x8*)&ph[(long)mt * 8192];                             \
      acc[4 + i] = __builtin_amdgcn_mfma_f32_16x16x32_bf16(Ahi.bf, bhi.bf, acc[4 + i], 0, 0, 0); \
    }                                                                           \
  }

__global__ __launch_bounds__(512, 6) void k1_qkv(
    const float* __restrict__ x,
    const unsigned short* __restrict__ WhiP, const unsigned short* __restrict__ WloP,
    const float* __restrict__ biasAll, float* __restrict__ qkv) {
  const int nt = blockIdx.x;           // 0..63
  const int b  = blockIdx.y;
  const int t  = threadIdx.x;
  const int lane = t & 63;
  const int wid  = t >> 6;             // 0..7
  const int mh4 = (wid >> 2) * 4;      // qk tile base: 0 or 4
  const int mh2 = (wid >> 2) * 2;      // v tile base:  0 or 2 (+8)
  const int nq  = wid & 3;             // n-tile within 64 cols
  const int q4  = lane >> 4;
  const int l16 = lane & 15;
  const int n0  = nt * 64;

  __shared__ unsigned short ldsHi[2][64][32];   // 8 KB
  __shared__ unsigned short ldsLo[2][64][32];   // 8 KB

  const int sn  = t & 63;
  const int skb = wid;                 // k-group of 4 within the 32-k step
  const float* xb = x + (long)b * NC * NSP + n0 + sn;
  // write slot: 16B-slot (skb>>1) swizzled by (sn&3), half-slot (skb&1)
  const int wslot = (((skb >> 1) ^ (sn & 3)) << 3) + ((skb & 1) << 2);
  const int nl = nq * 16 + l16;        // column within block tile
  const int rslot = ((q4 ^ (nl & 3)) << 3);

  f32x4 acc[6] = {};
  float xrA[4], xrB[4];
#pragma unroll
  for (int j = 0; j < 4; j++) xrA[j] = xb[(long)(skb * 4 + j) * NSP];
#pragma unroll
  for (int j = 0; j < 4; j++) xrB[j] = xb[(long)(32 + skb * 4 + j) * NSP];

  for (int s2 = 0; s2 < 16; s2 += 2) {
    K1_STEP(s2,     xrA, 0)
    K1_STEP(s2 + 1, xrB, 1)
  }

  // epilogue: C/D layout col=lane&15, row=(lane>>4)*4+reg
#pragma unroll
  for (int i = 0; i < 4; i++) {
    const int mt = mh4 + i;
    const int n = n0 + nl;
#pragma unroll
    for (int r = 0; r < 4; r++) {
      const int mrow = mt * 16 + q4 * 4 + r;
      qkv[(long)(b * NM + mrow) * NSP + n] = acc[i][r] + biasAll[mrow];
    }
  }
#pragma unroll
  for (int i = 0; i < 2; i++) {
    const int mt = 8 + mh2 + i;
    const int n = n0 + nl;
#pragma unroll
    for (int r = 0; r < 4; r++) {
      const int mrow = mt * 16 + q4 * 4 + r;
      qkv[(long)(b * NM + mrow) * NSP + n] = acc[4 + i][r] + biasAll[mrow];
    }
  }
}

// ---------------- K2a: partial logits, fp32. Grid (16 ch, 16 b) ----------------
__global__ __launch_bounds__(256) void k2a_logits(const float* __restrict__ qkv,
                                                  float* __restrict__ part) {
  const int ch = blockIdx.x;   // 0..15, each covers 256 spatial
  const int b  = blockIdx.y;
  const int t  = threadIdx.x;
  __shared__ float ldsQ[64][68];
  __shared__ float ldsKT[64][68];
  const float* Qb = qkv + (long)(b * NM) * NSP;
  const float* Kb = Qb + (long)NCB * NSP;
  const int cc0 = (t >> 4) << 2, dd0 = (t & 15) << 2;
  float acc[4][4] = {};

  for (int s = 0; s < 4; s++) {
    const int n0 = ch * 256 + s * 64;
    __syncthreads();
    for (int i = t; i < 1024; i += 256) {
      int r = i >> 4, c4 = (i & 15) << 2;
      *(f32x4*)&ldsQ[r][c4] = *(const f32x4*)&Qb[(long)r * NSP + n0 + c4];
      f32x4 u = *(const f32x4*)&Kb[(long)r * NSP + n0 + c4];
      ldsKT[c4 + 0][r] = u[0]; ldsKT[c4 + 1][r] = u[1];
      ldsKT[c4 + 2][r] = u[2]; ldsKT[c4 + 3][r] = u[3];
    }
    __syncthreads();
    for (int n = 0; n < 64; n += 4) {
      f32x4 qv[4], kv[4];
#pragma unroll
      for (int i = 0; i < 4; i++) qv[i] = *(const f32x4*)&ldsQ[cc0 + i][n];
#pragma unroll
      for (int p = 0; p < 4; p++) kv[p] = *(const f32x4*)&ldsKT[n + p][dd0];
#pragma unroll
      for (int i = 0; i < 4; i++)
#pragma unroll
        for (int p = 0; p < 4; p++) {
          float qq = qv[i][p];
          acc[i][0] += qq * kv[p][0]; acc[i][1] += qq * kv[p][1];
          acc[i][2] += qq * kv[p][2]; acc[i][3] += qq * kv[p][3];
        }
    }
  }
  float* dst = part + (long)(b * 16 + ch) * 4096;
#pragma unroll
  for (int i = 0; i < 4; i++)
#pragma unroll
    for (int j = 0; j < 4; j++)
      dst[(cc0 + i) * 64 + dd0 + j] = acc[i][j];
}

// ---------------- K2b: reduce 16 partials + softmax, one wave per row ----------------
__global__ __launch_bounds__(64) void k2b_softmax(const float* __restrict__ part,
                                                  float* __restrict__ attn) {
  const int row = blockIdx.x;      // 0..63
  const int b   = blockIdx.y;
  const int d   = threadIdx.x;     // 0..63
  float s = 0.f;
  const float* p = part + (long)b * 16 * 4096 + row * 64 + d;
#pragma unroll
  for (int c = 0; c < 16; c++) s += p[(long)c * 4096];
  // wave softmax
  float mx = s;
#pragma unroll
  for (int o = 32; o; o >>= 1) mx = fmaxf(mx, __shfl_xor(mx, o, 64));
  float e = __expf(s - mx);
  float sum = e;
#pragma unroll
  for (int o = 32; o; o >>= 1) sum += __shfl_xor(sum, o, 64);
  attn[(long)(b * 64 + row) * 64 + d] = e / sum;
}

// ---------------- K2c: M' = gamma * Wo @ attn ----------------
__global__ __launch_bounds__(256) void k2c_mprime(const float* __restrict__ attn,
    const float* __restrict__ wo, const float* __restrict__ gamma,
    float* __restrict__ Mp) {
  const int cb = blockIdx.x;
  const int b  = blockIdx.y;
  const int t  = threadIdx.x;
  __shared__ float ldsW[64][68];
  __shared__ float ldsA[64][68];
  for (int i = t; i < 1024; i += 256) {
    int r = i >> 4, c4 = (i & 15) << 2;
    *(f32x4*)&ldsW[r][c4] = *(const f32x4*)&wo[(long)(cb * 64 + r) * 64 + c4];
    *(f32x4*)&ldsA[r][c4] = *(const f32x4*)&attn[(long)(b * 64 + r) * 64 + c4];
  }
  __syncthreads();
  const int cc0 = (t >> 4) << 2, dd0 = (t & 15) << 2;
  float acc[4][4] = {};
  for (int e = 0; e < 64; e += 4) {
    f32x4 wv4[4], av[4];
#pragma unroll
    for (int i = 0; i < 4; i++) wv4[i] = *(const f32x4*)&ldsW[cc0 + i][e];
#pragma unroll
    for (int p = 0; p < 4; p++) av[p] = *(const f32x4*)&ldsA[e + p][dd0];
#pragma unroll
    for (int i = 0; i < 4; i++)
#pragma unroll
      for (int p = 0; p < 4; p++) {
        float ww = wv4[i][p];
        acc[i][0] += ww * av[p][0]; acc[i][1] += ww * av[p][1];
        acc[i][2] += ww * av[p][2]; acc[i][3] += ww * av[p][3];
      }
  }
  const float g = gamma[0];
  float* dst = Mp + (long)(b * NC + cb * 64) * 64;
#pragma unroll
  for (int i = 0; i < 4; i++)
#pragma unroll
    for (int j = 0; j < 4; j++)
      dst[(cc0 + i) * 64 + dd0 + j] = g * acc[i][j];
}

// ---------------- K3: out = M' @ V + gamma*b_o + x ----------------
__global__ __launch_bounds__(256, 3) void k3_out(const float* __restrict__ qkv,
    const float* __restrict__ Mp, const float* __restrict__ x,
    const float* __restrict__ bo, const float* __restrict__ gamma,
    float* __restrict__ out) {
  const int nt = blockIdx.x;
  const int ct = blockIdx.y;
  const int b  = blockIdx.z;
  const int t  = threadIdx.x;
  const int n0 = nt * 128, c0 = ct * 128;
  __shared__ float ldsM[128][68];
  __shared__ float ldsV[32][128];
  const float* Vb = qkv + (long)(b * NM + 128) * NSP;

  for (int k = 0; k < 8; k++) {
    int idx = k * 256 + t;
    int c = idx >> 4, dv = idx & 15;
    *(f32x4*)&ldsM[c][dv * 4] = *(const f32x4*)&Mp[(long)(b * NC + c0 + c) * 64 + dv * 4];
  }

  const int ci = t >> 4, ni = t & 15;
  f32x4 acc[8][2] = {};

  for (int vh = 0; vh < 2; vh++) {
    __syncthreads();
    for (int k = 0; k < 4; k++) {
      int idx = k * 256 + t;
      int row = idx >> 5, nv = idx & 31;
      *(f32x4*)&ldsV[row][nv * 4] =
          *(const f32x4*)&Vb[(long)(vh * 32 + row) * NSP + n0 + nv * 4];
    }
    __syncthreads();
    for (int dd = 0; dd < 32; dd += 4) {
      const int d = vh * 32 + dd;
      f32x4 mi[8];
#pragma unroll
      for (int i = 0; i < 8; i++) mi[i] = *(const f32x4*)&ldsM[ci + 16 * i][d];
#pragma unroll
      for (int p = 0; p < 4; p++) {
        f32x4 v0 = *(const f32x4*)&ldsV[dd + p][ni * 4];
        f32x4 v1 = *(const f32x4*)&ldsV[dd + p][ni * 4 + 64];
#pragma unroll
        for (int i = 0; i < 8; i++) {
          acc[i][0] += mi[i][p] * v0;
          acc[i][1] += mi[i][p] * v1;
        }
      }
    }
  }

  const float g = gamma[0];
#pragma unroll
  for (int i = 0; i < 8; i++) {
    const int c = c0 + ci + 16 * i;
    const float bb = g * bo[c];
#pragma unroll
    for (int h = 0; h < 2; h++) {
      long off = (long)(b * NC + c) * NSP + n0 + ni * 4 + h * 64;
      f32x4 xr = *(const f32x4*)&x[off];
      f32x4 o = acc[i][h] + xr + bb;
      *(f32x4*)&out[off] = o;
    }
  }
}

extern "C" void kernel_launch(void* const* d_in, const int* in_sizes, int n_in,
                              void* d_out, int out_size, void* d_ws, size_t ws_size,
                              hipStream_t stream) {
  const float* x   = (const float*)d_in[0];
  const float* wq  = (const float*)d_in[1];
  const float* bq  = (const float*)d_in[2];
  const float* wk  = (const float*)d_in[3];
  const float* bk  = (const float*)d_in[4];
  const float* wv  = (const float*)d_in[5];
  const float* bv  = (const float*)d_in[6];
  const float* wo  = (const float*)d_in[7];
  const float* bo  = (const float*)d_in[8];
  const float* gm  = (const float*)d_in[9];
  float* out = (float*)d_out;
  float* ws  = (float*)d_ws;

  // ws carve (floats)
  float* qkv  = ws;                       // 192*4096*16 = 12,582,912
  float* part = ws + 12582912;            // 16*16*4096  = 1,048,576
  float* attn = ws + 13631488;            // 65,536
  float* Mp   = ws + 13697024;            // 524,288
  unsigned short* WhiP = (unsigned short*)(ws + 14221312);  // 12*16*64*8 u16
  unsigned short* WloP = (unsigned short*)(ws + 14270464);  //  8*16*64*8 u16
  float* biasAll = ws + 14303232;         // 192

  k0_wprep<<<384, 256, 0, stream>>>(wq, wk, wv, bq, bk, bv, WhiP, WloP, biasAll);
  k1_qkv<<<dim3(64, 16), 512, 0, stream>>>(x, WhiP, WloP, biasAll, qkv);
  k2a_logits<<<dim3(16, 16), 256, 0, stream>>>(qkv, part);
  k2b_softmax<<<dim3(64, 16), 64, 0, stream>>>(part, attn);
  k2c_mprime<<<dim3(8, 16), 256, 0, stream>>>(attn, wo, gm, Mp);
  k3_out<<<dim3(32, 4, 16), 256, 0, stream>>>(qkv, Mp, x, bo, gm, out);
}

// Round 3
// 378.887 us; speedup vs baseline: 1.0660x; 1.0660x over previous
//
#include <hip/hip_runtime.h>

// Conv2dSelfAttention: B=16, C=512, Cb=64, N=64*64=4096
// K0 W-prep: pack weights into MFMA fragment order (bf16 hi/lo) + bias concat
// K1 QKV: 192x128 tile (round-0 structure: 28 MFMA/wave/step), packed-A coalesced
//         loads, 2-way-max LDS swizzle, dbuf 1-barrier, 2-deep x prefetch
// K2a partial logits (512 thr, 2 wave-groups) -> K2b softmax -> K2c M' (256 blocks)
// K3 out = M'@V + gamma*b_o + x  (no ldsM -> 16 KB LDS, 4 blocks/CU)

#define NB  16
#define NC  512
#define NCB 64
#define NSP 4096
#define NM  192

typedef __bf16 bf16x8 __attribute__((ext_vector_type(8)));
typedef unsigned short u16x8 __attribute__((ext_vector_type(8)));
typedef float f32x4 __attribute__((ext_vector_type(4)));

union F8 { bf16x8 bf; u16x8 us; };

__device__ __forceinline__ unsigned short f2bfu(float f) {
  unsigned u = __builtin_bit_cast(unsigned, f);
  unsigned r = u + 0x7fffu + ((u >> 16) & 1u);   // RNE
  return (unsigned short)(r >> 16);
}
__device__ __forceinline__ float bfu2f(unsigned short h) {
  return __builtin_bit_cast(float, ((unsigned)h) << 16);
}

// ---------------- K0: pack weights to fragment order, bf16 hi/lo ----------------
// WhiP[((mt*16 + s)*64 + lane)*8 + j] = W[mt*16 + (lane&15)][s*32 + (lane>>4)*8 + j]
// -> K1 A-loads are 64 lanes x 16B = 1KB CONTIGUOUS per instruction.
// hi: mt 0..11 (q,k,v rows 0..191); lo: mt 0..7 only (q,k).
__global__ __launch_bounds__(256) void k0_wprep(
    const float* __restrict__ wq, const float* __restrict__ wk,
    const float* __restrict__ wv,
    const float* __restrict__ bq, const float* __restrict__ bk,
    const float* __restrict__ bv,
    unsigned short* __restrict__ WhiP, unsigned short* __restrict__ WloP,
    float* __restrict__ biasAll) {
  int i = blockIdx.x * 256 + threadIdx.x;        // 0 .. 98303
  if (i < 12 * 16 * 64 * 8) {
    int j    = i & 7;
    int lane = (i >> 3) & 63;
    int s    = (i >> 9) & 15;
    int mt   = i >> 13;                          // 0..11
    int row = mt * 16 + (lane & 15);             // 0..191
    int col = s * 32 + (lane >> 4) * 8 + j;      // 0..511
    float f = (row < 64)  ? wq[row * NC + col]
            : (row < 128) ? wk[(row - 64) * NC + col]
                          : wv[(row - 128) * NC + col];
    unsigned short h = f2bfu(f);
    WhiP[i] = h;
    if (i < 8 * 16 * 64 * 8)                     // mt < 8 : q,k lo part
      WloP[i] = f2bfu(f - bfu2f(h));
  }
  if (i < 192) {
    biasAll[i] = (i < 64) ? bq[i] : (i < 128) ? bk[i - 64] : bv[i - 128];
  }
}

// ---------------- K1: QKV = Wqkv @ X_b ----------------
// Grid (32 nt, 16 b), 512 thr. Tile 192m x 128n, K=512 in 16 steps of 32.
// Staging: thread (sn=t&127, skb=t>>7) loads 8 k-strided floats (n-coalesced),
// converts hi/lo, writes ONE u16x8 each to swizzled slot
//   wslot = skb ^ (sn&3) ^ ((sn>>2)&3)
// (verified <=2-way bank alias on both the b128 write and the fragment read;
//  round-0's skb^(sn&3) was 4-way on both). Double-buffered, 1 barrier/step,
// 2-deep register prefetch (xrA/xrB, loop 2x-unrolled so indexing is static).
// Wave (mh,nq): 4 qk m-tiles x 2 n-tiles x 3 split-MFMA + 2 v m-tiles x 2 x 1
// = 28 MFMA/wave/step. A-loads from packed layout: 1KB contiguous coalesced.
#define K1_STEP(S, XR, BUF)                                                     \
  {                                                                             \
    F8 hi, lo;                                                                  \
    _Pragma("unroll")                                                           \
    for (int j = 0; j < 8; j++) {                                               \
      unsigned short h = f2bfu(XR[j]);                                          \
      hi.us[j] = h;                                                             \
      lo.us[j] = f2bfu(XR[j] - bfu2f(h));                                       \
    }                                                                           \
    ldsHi[BUF][sn][wslot] = hi.us;                                              \
    ldsLo[BUF][sn][wslot] = lo.us;                                              \
    __syncthreads();                                                            \
    if ((S) < 14) {                                                             \
      const float* src = xb + (long)(((S) + 2) * 32 + skb * 8) * NSP;           \
      _Pragma("unroll")                                                         \
      for (int j = 0; j < 8; j++) XR[j] = src[(long)j * NSP];                   \
    }                                                                           \
    F8 bhi[2], blo[2];                                                          \
    _Pragma("unroll")                                                           \
    for (int ni = 0; ni < 2; ni++) {                                            \
      const int nl = nq * 32 + ni * 16 + l16;                                   \
      const int slot = q4 ^ (nl & 3) ^ ((nl >> 2) & 3);                         \
      bhi[ni].us = ldsHi[BUF][nl][slot];                                        \
      blo[ni].us = ldsLo[BUF][nl][slot];                                        \
    }                                                                           \
    const unsigned short* ph = WhiP + (long)(S) * 512 + (long)lane * 8;         \
    const unsigned short* pl = WloP + (long)(S) * 512 + (long)lane * 8;         \
    _Pragma("unroll")                                                           \
    for (int i = 0; i < 4; i++) {                                               \
      const int mt = mh * 4 + i;                                                \
      F8 Ahi, Alo;                                                              \
      Ahi.us = *(const u16x8*)&ph[(long)mt * 8192];                             \
      Alo.us = *(const u16x8*)&pl[(long)mt * 8192];                             \
      _Pragma("unroll")                                                         \
      for (int ni = 0; ni < 2; ni++) {                                          \
        const int a = i * 2 + ni;                                               \
        acc[a] = __builtin_amdgcn_mfma_f32_16x16x32_bf16(Ahi.bf, bhi[ni].bf, acc[a], 0, 0, 0); \
        acc[a] = __builtin_amdgcn_mfma_f32_16x16x32_bf16(Ahi.bf, blo[ni].bf, acc[a], 0, 0, 0); \
        acc[a] = __builtin_amdgcn_mfma_f32_16x16x32_bf16(Alo.bf, bhi[ni].bf, acc[a], 0, 0, 0); \
      }                                                                         \
    }                                                                           \
    _Pragma("unroll")                                                           \
    for (int i = 0; i < 2; i++) {                                               \
      const int mt = 8 + mh * 2 + i;                                            \
      F8 Ahi;                                                                   \
      Ahi.us = *(const u16x8*)&ph[(long)mt * 8192];                             \
      _Pragma("unroll")                                                         \
      for (int ni = 0; ni < 2; ni++) {                                          \
        const int a = 8 + i * 2 + ni;                                           \
        acc[a] = __builtin_amdgcn_mfma_f32_16x16x32_bf16(Ahi.bf, bhi[ni].bf, acc[a], 0, 0, 0); \
      }                                                                         \
    }                                                                           \
  }

__global__ __launch_bounds__(512, 4) void k1_qkv(
    const float* __restrict__ x,
    const unsigned short* __restrict__ WhiP, const unsigned short* __restrict__ WloP,
    const float* __restrict__ biasAll, float* __restrict__ qkv) {
  const int nt = blockIdx.x;           // 0..31
  const int b  = blockIdx.y;
  const int t  = threadIdx.x;
  const int lane = t & 63;
  const int wid  = t >> 6;             // 0..7
  const int mh = wid >> 2;             // 0,1
  const int nq = wid & 3;              // 0..3
  const int q4  = lane >> 4;
  const int l16 = lane & 15;
  const int n0  = nt * 128;

  __shared__ u16x8 ldsHi[2][128][4];   // 16 KB
  __shared__ u16x8 ldsLo[2][128][4];   // 16 KB

  const int sn  = t & 127;
  const int skb = t >> 7;              // 0..3
  const float* xb = x + (long)b * NC * NSP + n0 + sn;
  const int wslot = skb ^ (sn & 3) ^ ((sn >> 2) & 3);

  f32x4 acc[12] = {};
  float xrA[8], xrB[8];
#pragma unroll
  for (int j = 0; j < 8; j++) xrA[j] = xb[(long)(skb * 8 + j) * NSP];
#pragma unroll
  for (int j = 0; j < 8; j++) xrB[j] = xb[(long)(32 + skb * 8 + j) * NSP];

  for (int s2 = 0; s2 < 16; s2 += 2) {
    K1_STEP(s2,     xrA, 0)
    K1_STEP(s2 + 1, xrB, 1)
  }

  // epilogue: C/D layout col=lane&15, row=(lane>>4)*4+reg
#pragma unroll
  for (int i = 0; i < 4; i++) {
    const int mt = mh * 4 + i;
#pragma unroll
    for (int ni = 0; ni < 2; ni++) {
      const int n = n0 + nq * 32 + ni * 16 + l16;
#pragma unroll
      for (int r = 0; r < 4; r++) {
        const int mrow = mt * 16 + q4 * 4 + r;
        qkv[(long)(b * NM + mrow) * NSP + n] = acc[i * 2 + ni][r] + biasAll[mrow];
      }
    }
  }
#pragma unroll
  for (int i = 0; i < 2; i++) {
    const int mt = 8 + mh * 2 + i;
#pragma unroll
    for (int ni = 0; ni < 2; ni++) {
      const int n = n0 + nq * 32 + ni * 16 + l16;
#pragma unroll
      for (int r = 0; r < 4; r++) {
        const int mrow = mt * 16 + q4 * 4 + r;
        qkv[(long)(b * NM + mrow) * NSP + n] = acc[8 + i * 2 + ni][r] + biasAll[mrow];
      }
    }
  }
}

// ---------------- K2a: partial logits, fp32. Grid (16 ch, 16 b), 512 thr ----------------
// Two wave-groups (g = t>>8): group g covers k-steps {2g, 2g+1}; cross-group
// LDS reduce at the end. 8 waves/block (was 4), 2 serial steps (was 4).
__global__ __launch_bounds__(512) void k2a_logits(const float* __restrict__ qkv,
                                                  float* __restrict__ part) {
  const int ch = blockIdx.x;   // 0..15, each covers 256 spatial
  const int b  = blockIdx.y;
  const int t  = threadIdx.x;
  const int g  = t >> 8;       // 0,1
  const int tl = t & 255;
  __shared__ float ldsQ[2][64][68];
  __shared__ float ldsKT[2][64][68];
  const float* Qb = qkv + (long)(b * NM) * NSP;
  const float* Kb = Qb + (long)NCB * NSP;
  const int cc0 = (tl >> 4) << 2, dd0 = (tl & 15) << 2;
  float acc[4][4] = {};

  for (int s = 0; s < 2; s++) {
    const int n0 = ch * 256 + (g * 2 + s) * 64;
    __syncthreads();
    for (int i = tl; i < 1024; i += 256) {
      int r = i >> 4, c4 = (i & 15) << 2;
      *(f32x4*)&ldsQ[g][r][c4] = *(const f32x4*)&Qb[(long)r * NSP + n0 + c4];
      f32x4 u = *(const f32x4*)&Kb[(long)r * NSP + n0 + c4];
      ldsKT[g][c4 + 0][r] = u[0]; ldsKT[g][c4 + 1][r] = u[1];
      ldsKT[g][c4 + 2][r] = u[2]; ldsKT[g][c4 + 3][r] = u[3];
    }
    __syncthreads();
    for (int n = 0; n < 64; n += 4) {
      f32x4 qv[4], kv[4];
#pragma unroll
      for (int i = 0; i < 4; i++) qv[i] = *(const f32x4*)&ldsQ[g][cc0 + i][n];
#pragma unroll
      for (int p = 0; p < 4; p++) kv[p] = *(const f32x4*)&ldsKT[g][n + p][dd0];
#pragma unroll
      for (int i = 0; i < 4; i++)
#pragma unroll
        for (int p = 0; p < 4; p++) {
          float qq = qv[i][p];
          acc[i][0] += qq * kv[p][0]; acc[i][1] += qq * kv[p][1];
          acc[i][2] += qq * kv[p][2]; acc[i][3] += qq * kv[p][3];
        }
    }
  }

  // cross-group reduce: group 1 parks its acc in LDS, group 0 adds and writes.
  __syncthreads();
  float* scratch = &ldsQ[0][0][0];     // 16 KB needed, reuse
  if (g == 1) {
#pragma unroll
    for (int i = 0; i < 4; i++)
#pragma unroll
      for (int j = 0; j < 4; j++)
        scratch[tl + 256 * (i * 4 + j)] = acc[i][j];
  }
  __syncthreads();
  if (g == 0) {
    float* dst = part + (long)(b * 16 + ch) * 4096;
#pragma unroll
    for (int i = 0; i < 4; i++)
#pragma unroll
      for (int j = 0; j < 4; j++)
        dst[(cc0 + i) * 64 + dd0 + j] = acc[i][j] + scratch[tl + 256 * (i * 4 + j)];
  }
}

// ---------------- K2b: reduce 16 partials + softmax, one wave per row ----------------
__global__ __launch_bounds__(64) void k2b_softmax(const float* __restrict__ part,
                                                  float* __restrict__ attn) {
  const int row = blockIdx.x;      // 0..63
  const int b   = blockIdx.y;
  const int d   = threadIdx.x;     // 0..63
  float s = 0.f;
  const float* p = part + (long)b * 16 * 4096 + row * 64 + d;
#pragma unroll
  for (int c = 0; c < 16; c++) s += p[(long)c * 4096];
  // wave softmax
  float mx = s;
#pragma unroll
  for (int o = 32; o; o >>= 1) mx = fmaxf(mx, __shfl_xor(mx, o, 64));
  float e = __expf(s - mx);
  float sum = e;
#pragma unroll
  for (int o = 32; o; o >>= 1) sum += __shfl_xor(sum, o, 64);
  attn[(long)(b * 64 + row) * 64 + d] = e / sum;
}

// ---------------- K2c: M' = gamma * Wo @ attn. Grid (16, 16): 32-row tiles ----------------
__global__ __launch_bounds__(256) void k2c_mprime(const float* __restrict__ attn,
    const float* __restrict__ wo, const float* __restrict__ gamma,
    float* __restrict__ Mp) {
  const int cb = blockIdx.x;       // 0..15, rows cb*32..cb*32+31
  const int b  = blockIdx.y;
  const int t  = threadIdx.x;
  __shared__ float ldsW[32][68];
  __shared__ float ldsA[64][68];
  for (int i = t; i < 512; i += 256) {
    int r = i >> 4, c4 = (i & 15) << 2;
    *(f32x4*)&ldsW[r][c4] = *(const f32x4*)&wo[(long)(cb * 32 + r) * 64 + c4];
  }
  for (int i = t; i < 1024; i += 256) {
    int r = i >> 4, c4 = (i & 15) << 2;
    *(f32x4*)&ldsA[r][c4] = *(const f32x4*)&attn[(long)(b * 64 + r) * 64 + c4];
  }
  __syncthreads();
  const int cc0 = (t >> 4) << 1, dd0 = (t & 15) << 2;
  float acc[2][4] = {};
  for (int e = 0; e < 64; e += 4) {
    f32x4 wv2[2], av[4];
#pragma unroll
    for (int i = 0; i < 2; i++) wv2[i] = *(const f32x4*)&ldsW[cc0 + i][e];
#pragma unroll
    for (int p = 0; p < 4; p++) av[p] = *(const f32x4*)&ldsA[e + p][dd0];
#pragma unroll
    for (int i = 0; i < 2; i++)
#pragma unroll
      for (int p = 0; p < 4; p++) {
        float ww = wv2[i][p];
        acc[i][0] += ww * av[p][0]; acc[i][1] += ww * av[p][1];
        acc[i][2] += ww * av[p][2]; acc[i][3] += ww * av[p][3];
      }
  }
  const float g = gamma[0];
  float* dst = Mp + (long)(b * NC + cb * 32) * 64;
#pragma unroll
  for (int i = 0; i < 2; i++)
#pragma unroll
    for (int j = 0; j < 4; j++)
      dst[(cc0 + i) * 64 + dd0 + j] = g * acc[i][j];
}

// ---------------- K3: out = M' @ V + gamma*b_o + x ----------------
// No ldsM: Mp tile (32 KB, L1/L2-resident) read direct from global with
// quarter-wave-broadcast addresses. LDS = 16 KB -> 4 blocks/CU, 16 waves.
__global__ __launch_bounds__(256, 4) void k3_out(const float* __restrict__ qkv,
    const float* __restrict__ Mp, const float* __restrict__ x,
    const float* __restrict__ bo, const float* __restrict__ gamma,
    float* __restrict__ out) {
  const int nt = blockIdx.x;
  const int ct = blockIdx.y;
  const int b  = blockIdx.z;
  const int t  = threadIdx.x;
  const int n0 = nt * 128, c0 = ct * 128;
  __shared__ float ldsV[32][128];      // 16 KB
  const float* Vb  = qkv + (long)(b * NM + 128) * NSP;
  const float* MpB = Mp + (long)(b * NC + c0) * 64;

  const int ci = t >> 4, ni = t & 15;
  f32x4 acc[8][2] = {};

  for (int vh = 0; vh < 2; vh++) {
    __syncthreads();
    for (int k = 0; k < 4; k++) {
      int idx = k * 256 + t;
      int row = idx >> 5, nv = idx & 31;
      *(f32x4*)&ldsV[row][nv * 4] =
          *(const f32x4*)&Vb[(long)(vh * 32 + row) * NSP + n0 + nv * 4];
    }
    __syncthreads();
    for (int dd = 0; dd < 32; dd += 4) {
      const int d = vh * 32 + dd;
#pragma unroll
      for (int h = 0; h < 2; h++) {
        f32x4 mi[4];
#pragma unroll
        for (int i4 = 0; i4 < 4; i4++)
          mi[i4] = *(const f32x4*)&MpB[(long)(ci + 16 * (h * 4 + i4)) * 64 + d];
#pragma unroll
        for (int p = 0; p < 4; p++) {
          f32x4 v0 = *(const f32x4*)&ldsV[dd + p][ni * 4];
          f32x4 v1 = *(const f32x4*)&ldsV[dd + p][ni * 4 + 64];
#pragma unroll
          for (int i4 = 0; i4 < 4; i4++) {
            acc[h * 4 + i4][0] += mi[i4][p] * v0;
            acc[h * 4 + i4][1] += mi[i4][p] * v1;
          }
        }
      }
    }
  }

  const float g = gamma[0];
#pragma unroll
  for (int i = 0; i < 8; i++) {
    const int c = c0 + ci + 16 * i;
    const float bb = g * bo[c];
#pragma unroll
    for (int h = 0; h < 2; h++) {
      long off = (long)(b * NC + c) * NSP + n0 + ni * 4 + h * 64;
      f32x4 xr = *(const f32x4*)&x[off];
      f32x4 o = acc[i][h] + xr + bb;
      *(f32x4*)&out[off] = o;
    }
  }
}

extern "C" void kernel_launch(void* const* d_in, const int* in_sizes, int n_in,
                              void* d_out, int out_size, void* d_ws, size_t ws_size,
                              hipStream_t stream) {
  const float* x   = (const float*)d_in[0];
  const float* wq  = (const float*)d_in[1];
  const float* bq  = (const float*)d_in[2];
  const float* wk  = (const float*)d_in[3];
  const float* bk  = (const float*)d_in[4];
  const float* wv  = (const float*)d_in[5];
  const float* bv  = (const float*)d_in[6];
  const float* wo  = (const float*)d_in[7];
  const float* bo  = (const float*)d_in[8];
  const float* gm  = (const float*)d_in[9];
  float* out = (float*)d_out;
  float* ws  = (float*)d_ws;

  // ws carve (floats)
  float* qkv  = ws;                       // 192*4096*16 = 12,582,912
  float* part = ws + 12582912;            // 16*16*4096  = 1,048,576
  float* attn = ws + 13631488;            // 65,536
  float* Mp   = ws + 13697024;            // 524,288
  unsigned short* WhiP = (unsigned short*)(ws + 14221312);  // 12*16*64*8 u16
  unsigned short* WloP = (unsigned short*)(ws + 14270464);  //  8*16*64*8 u16
  float* biasAll = ws + 14303232;         // 192

  k0_wprep<<<384, 256, 0, stream>>>(wq, wk, wv, bq, bk, bv, WhiP, WloP, biasAll);
  k1_qkv<<<dim3(32, 16), 512, 0, stream>>>(x, WhiP, WloP, biasAll, qkv);
  k2a_logits<<<dim3(16, 16), 512, 0, stream>>>(qkv, part);
  k2b_softmax<<<dim3(64, 16), 64, 0, stream>>>(part, attn);
  k2c_mprime<<<dim3(16, 16), 256, 0, stream>>>(attn, wo, gm, Mp);
  k3_out<<<dim3(32, 4, 16), 256, 0, stream>>>(qkv, Mp, x, bo, gm, out);
}

// Round 4
// 337.162 us; speedup vs baseline: 1.1979x; 1.1238x over previous
//
#include <hip/hip_runtime.h>

// Conv2dSelfAttention: B=16, C=512, Cb=64, N=64*64=4096
// K0 W-prep: pack weights into MFMA fragment order (bf16 hi/lo) + bias concat
// K1 QKV: 192x128 tile, packed-A coalesced loads, 2-way LDS swizzle, dbuf,
//         2-deep prefetch. Q,K -> qkv fp32 (128 rows); V -> Vphi/Vplo bf16 [n][d]
// K2a partial logits -> K2b softmax -> K2c M' -> MpPhi/MpPlo bf16 A-frag packed
// K3 out = M'@V (split-bf16 MFMA) + gamma*b_o + x

#define NB  16
#define NC  512
#define NCB 64
#define NSP 4096
#define NMQ 128   // q,k rows kept in fp32 qkv

typedef __bf16 bf16x8 __attribute__((ext_vector_type(8)));
typedef unsigned short u16x8 __attribute__((ext_vector_type(8)));
typedef unsigned short u16x4 __attribute__((ext_vector_type(4)));
typedef float f32x4 __attribute__((ext_vector_type(4)));

union F8 { bf16x8 bf; u16x8 us; };
union U4 { u16x4 v; unsigned short a[4]; };

__device__ __forceinline__ unsigned short f2bfu(float f) {
  unsigned u = __builtin_bit_cast(unsigned, f);
  unsigned r = u + 0x7fffu + ((u >> 16) & 1u);   // RNE
  return (unsigned short)(r >> 16);
}
__device__ __forceinline__ float bfu2f(unsigned short h) {
  return __builtin_bit_cast(float, ((unsigned)h) << 16);
}

// ---------------- K0: pack weights to fragment order, bf16 hi/lo ----------------
// WhiP[((mt*16 + s)*64 + lane)*8 + j] = W[mt*16 + (lane&15)][s*32 + (lane>>4)*8 + j]
// -> K1 A-loads are 64 lanes x 16B = 1KB CONTIGUOUS per instruction.
// hi: mt 0..11 (q,k,v rows 0..191); lo: mt 0..7 only (q,k).
__global__ __launch_bounds__(256) void k0_wprep(
    const float* __restrict__ wq, const float* __restrict__ wk,
    const float* __restrict__ wv,
    const float* __restrict__ bq, const float* __restrict__ bk,
    const float* __restrict__ bv,
    unsigned short* __restrict__ WhiP, unsigned short* __restrict__ WloP,
    float* __restrict__ biasAll) {
  int i = blockIdx.x * 256 + threadIdx.x;        // 0 .. 98303
  if (i < 12 * 16 * 64 * 8) {
    int j    = i & 7;
    int lane = (i >> 3) & 63;
    int s    = (i >> 9) & 15;
    int mt   = i >> 13;                          // 0..11
    int row = mt * 16 + (lane & 15);             // 0..191
    int col = s * 32 + (lane >> 4) * 8 + j;      // 0..511
    float f = (row < 64)  ? wq[row * NC + col]
            : (row < 128) ? wk[(row - 64) * NC + col]
                          : wv[(row - 128) * NC + col];
    unsigned short h = f2bfu(f);
    WhiP[i] = h;
    if (i < 8 * 16 * 64 * 8)                     // mt < 8 : q,k lo part
      WloP[i] = f2bfu(f - bfu2f(h));
  }
  if (i < 192) {
    biasAll[i] = (i < 64) ? bq[i] : (i < 128) ? bk[i - 64] : bv[i - 128];
  }
}

// ---------------- K1: QKV = Wqkv @ X_b ----------------
// Grid (32 nt, 16 b), 512 thr. Tile 192m x 128n, K=512 in 16 steps of 32.
// Q,K rows (0..127) -> qkv fp32. V rows -> Vphi/Vplo bf16, TRANSPOSED [n][d]
// (B-fragment-friendly for K3's MFMA).
#define K1_STEP(S, XR, BUF)                                                     \
  {                                                                             \
    F8 hi, lo;                                                                  \
    _Pragma("unroll")                                                           \
    for (int j = 0; j < 8; j++) {                                               \
      unsigned short h = f2bfu(XR[j]);                                          \
      hi.us[j] = h;                                                             \
      lo.us[j] = f2bfu(XR[j] - bfu2f(h));                                       \
    }                                                                           \
    ldsHi[BUF][sn][wslot] = hi.us;                                              \
    ldsLo[BUF][sn][wslot] = lo.us;                                              \
    __syncthreads();                                                            \
    if ((S) < 14) {                                                             \
      const float* src = xb + (long)(((S) + 2) * 32 + skb * 8) * NSP;           \
      _Pragma("unroll")                                                         \
      for (int j = 0; j < 8; j++) XR[j] = src[(long)j * NSP];                   \
    }                                                                           \
    F8 bhi[2], blo[2];                                                          \
    _Pragma("unroll")                                                           \
    for (int ni = 0; ni < 2; ni++) {                                            \
      const int nl = nq * 32 + ni * 16 + l16;                                   \
      const int slot = q4 ^ (nl & 3) ^ ((nl >> 2) & 3);                         \
      bhi[ni].us = ldsHi[BUF][nl][slot];                                        \
      blo[ni].us = ldsLo[BUF][nl][slot];                                        \
    }                                                                           \
    const unsigned short* ph = WhiP + (long)(S) * 512 + (long)lane * 8;         \
    const unsigned short* pl = WloP + (long)(S) * 512 + (long)lane * 8;         \
    _Pragma("unroll")                                                           \
    for (int i = 0; i < 4; i++) {                                               \
      const int mt = mh * 4 + i;                                                \
      F8 Ahi, Alo;                                                              \
      Ahi.us = *(const u16x8*)&ph[(long)mt * 8192];                             \
      Alo.us = *(const u16x8*)&pl[(long)mt * 8192];                             \
      _Pragma("unroll")                                                         \
      for (int ni = 0; ni < 2; ni++) {                                          \
        const int a = i * 2 + ni;                                               \
        acc[a] = __builtin_amdgcn_mfma_f32_16x16x32_bf16(Ahi.bf, bhi[ni].bf, acc[a], 0, 0, 0); \
        acc[a] = __builtin_amdgcn_mfma_f32_16x16x32_bf16(Ahi.bf, blo[ni].bf, acc[a], 0, 0, 0); \
        acc[a] = __builtin_amdgcn_mfma_f32_16x16x32_bf16(Alo.bf, bhi[ni].bf, acc[a], 0, 0, 0); \
      }                                                                         \
    }                                                                           \
    _Pragma("unroll")                                                           \
    for (int i = 0; i < 2; i++) {                                               \
      const int mt = 8 + mh * 2 + i;                                            \
      F8 Ahi;                                                                   \
      Ahi.us = *(const u16x8*)&ph[(long)mt * 8192];                             \
      _Pragma("unroll")                                                         \
      for (int ni = 0; ni < 2; ni++) {                                          \
        const int a = 8 + i * 2 + ni;                                           \
        acc[a] = __builtin_amdgcn_mfma_f32_16x16x32_bf16(Ahi.bf, bhi[ni].bf, acc[a], 0, 0, 0); \
      }                                                                         \
    }                                                                           \
  }

__global__ __launch_bounds__(512, 4) void k1_qkv(
    const float* __restrict__ x,
    const unsigned short* __restrict__ WhiP, const unsigned short* __restrict__ WloP,
    const float* __restrict__ biasAll, float* __restrict__ qkv,
    unsigned short* __restrict__ Vphi, unsigned short* __restrict__ Vplo) {
  const int nt = blockIdx.x;           // 0..31
  const int b  = blockIdx.y;
  const int t  = threadIdx.x;
  const int lane = t & 63;
  const int wid  = t >> 6;             // 0..7
  const int mh = wid >> 2;             // 0,1
  const int nq = wid & 3;              // 0..3
  const int q4  = lane >> 4;
  const int l16 = lane & 15;
  const int n0  = nt * 128;

  __shared__ u16x8 ldsHi[2][128][4];   // 16 KB
  __shared__ u16x8 ldsLo[2][128][4];   // 16 KB

  const int sn  = t & 127;
  const int skb = t >> 7;              // 0..3
  const float* xb = x + (long)b * NC * NSP + n0 + sn;
  const int wslot = skb ^ (sn & 3) ^ ((sn >> 2) & 3);

  f32x4 acc[12] = {};
  float xrA[8], xrB[8];
#pragma unroll
  for (int j = 0; j < 8; j++) xrA[j] = xb[(long)(skb * 8 + j) * NSP];
#pragma unroll
  for (int j = 0; j < 8; j++) xrB[j] = xb[(long)(32 + skb * 8 + j) * NSP];

  for (int s2 = 0; s2 < 16; s2 += 2) {
    K1_STEP(s2,     xrA, 0)
    K1_STEP(s2 + 1, xrB, 1)
  }

  // epilogue: C/D layout col=lane&15, row=(lane>>4)*4+reg
  // Q,K rows 0..127 -> qkv fp32
#pragma unroll
  for (int i = 0; i < 4; i++) {
    const int mt = mh * 4 + i;
#pragma unroll
    for (int ni = 0; ni < 2; ni++) {
      const int n = n0 + nq * 32 + ni * 16 + l16;
#pragma unroll
      for (int r = 0; r < 4; r++) {
        const int mrow = mt * 16 + q4 * 4 + r;
        qkv[(long)(b * NMQ + mrow) * NSP + n] = acc[i * 2 + ni][r] + biasAll[mrow];
      }
    }
  }
  // V rows -> bf16 hi/lo transposed [n][d]; thread holds 4 consecutive d
#pragma unroll
  for (int i = 0; i < 2; i++) {
    const int mt = 8 + mh * 2 + i;
    const int d0 = (mh * 2 + i) * 16 + q4 * 4;       // 0..63
#pragma unroll
    for (int ni = 0; ni < 2; ni++) {
      const int n = n0 + nq * 32 + ni * 16 + l16;
      U4 hv, lv;
#pragma unroll
      for (int r = 0; r < 4; r++) {
        const int mrow = mt * 16 + q4 * 4 + r;
        float v = acc[8 + i * 2 + ni][r] + biasAll[mrow];
        unsigned short h = f2bfu(v);
        hv.a[r] = h;
        lv.a[r] = f2bfu(v - bfu2f(h));
      }
      long off = ((long)b * NSP + n) * 64 + d0;
      *(u16x4*)&Vphi[off] = hv.v;
      *(u16x4*)&Vplo[off] = lv.v;
    }
  }
}

// ---------------- K2a: partial logits, fp32. Grid (16 ch, 16 b), 512 thr ----------------
__global__ __launch_bounds__(512) void k2a_logits(const float* __restrict__ qkv,
                                                  float* __restrict__ part) {
  const int ch = blockIdx.x;   // 0..15, each covers 256 spatial
  const int b  = blockIdx.y;
  const int t  = threadIdx.x;
  const int g  = t >> 8;       // 0,1
  const int tl = t & 255;
  __shared__ float ldsQ[2][64][68];
  __shared__ float ldsKT[2][64][68];
  const float* Qb = qkv + (long)(b * NMQ) * NSP;
  const float* Kb = Qb + (long)NCB * NSP;
  const int cc0 = (tl >> 4) << 2, dd0 = (tl & 15) << 2;
  float acc[4][4] = {};

  for (int s = 0; s < 2; s++) {
    const int n0 = ch * 256 + (g * 2 + s) * 64;
    __syncthreads();
    for (int i = tl; i < 1024; i += 256) {
      int r = i >> 4, c4 = (i & 15) << 2;
      *(f32x4*)&ldsQ[g][r][c4] = *(const f32x4*)&Qb[(long)r * NSP + n0 + c4];
      f32x4 u = *(const f32x4*)&Kb[(long)r * NSP + n0 + c4];
      ldsKT[g][c4 + 0][r] = u[0]; ldsKT[g][c4 + 1][r] = u[1];
      ldsKT[g][c4 + 2][r] = u[2]; ldsKT[g][c4 + 3][r] = u[3];
    }
    __syncthreads();
    for (int n = 0; n < 64; n += 4) {
      f32x4 qv[4], kv[4];
#pragma unroll
      for (int i = 0; i < 4; i++) qv[i] = *(const f32x4*)&ldsQ[g][cc0 + i][n];
#pragma unroll
      for (int p = 0; p < 4; p++) kv[p] = *(const f32x4*)&ldsKT[g][n + p][dd0];
#pragma unroll
      for (int i = 0; i < 4; i++)
#pragma unroll
        for (int p = 0; p < 4; p++) {
          float qq = qv[i][p];
          acc[i][0] += qq * kv[p][0]; acc[i][1] += qq * kv[p][1];
          acc[i][2] += qq * kv[p][2]; acc[i][3] += qq * kv[p][3];
        }
    }
  }

  // cross-group reduce: group 1 parks its acc in LDS, group 0 adds and writes.
  __syncthreads();
  float* scratch = &ldsQ[0][0][0];     // 16 KB needed, reuse
  if (g == 1) {
#pragma unroll
    for (int i = 0; i < 4; i++)
#pragma unroll
      for (int j = 0; j < 4; j++)
        scratch[tl + 256 * (i * 4 + j)] = acc[i][j];
  }
  __syncthreads();
  if (g == 0) {
    float* dst = part + (long)(b * 16 + ch) * 4096;
#pragma unroll
    for (int i = 0; i < 4; i++)
#pragma unroll
      for (int j = 0; j < 4; j++)
        dst[(cc0 + i) * 64 + dd0 + j] = acc[i][j] + scratch[tl + 256 * (i * 4 + j)];
  }
}

// ---------------- K2b: reduce 16 partials + softmax, one wave per row ----------------
__global__ __launch_bounds__(64) void k2b_softmax(const float* __restrict__ part,
                                                  float* __restrict__ attn) {
  const int row = blockIdx.x;      // 0..63
  const int b   = blockIdx.y;
  const int d   = threadIdx.x;     // 0..63
  float s = 0.f;
  const float* p = part + (long)b * 16 * 4096 + row * 64 + d;
#pragma unroll
  for (int c = 0; c < 16; c++) s += p[(long)c * 4096];
  // wave softmax
  float mx = s;
#pragma unroll
  for (int o = 32; o; o >>= 1) mx = fmaxf(mx, __shfl_xor(mx, o, 64));
  float e = __expf(s - mx);
  float sum = e;
#pragma unroll
  for (int o = 32; o; o >>= 1) sum += __shfl_xor(sum, o, 64);
  attn[(long)(b * 64 + row) * 64 + d] = e / sum;
}

// ---------------- K2c: M' = gamma * Wo @ attn -> bf16 hi/lo, A-frag packed ----------------
// MpP layout mirrors K0: MpP[(((b*32 + ct)*2 + s)*64 + lane)*8 + j]
//   = M'[ct*16 + (lane&15)][s*32 + (lane>>4)*8 + j]
__global__ __launch_bounds__(256) void k2c_mprime(const float* __restrict__ attn,
    const float* __restrict__ wo, const float* __restrict__ gamma,
    unsigned short* __restrict__ MpPhi, unsigned short* __restrict__ MpPlo) {
  const int cb = blockIdx.x;       // 0..15, rows cb*32..cb*32+31
  const int b  = blockIdx.y;
  const int t  = threadIdx.x;
  __shared__ float ldsW[32][68];
  __shared__ float ldsA[64][68];
  for (int i = t; i < 512; i += 256) {
    int r = i >> 4, c4 = (i & 15) << 2;
    *(f32x4*)&ldsW[r][c4] = *(const f32x4*)&wo[(long)(cb * 32 + r) * 64 + c4];
  }
  for (int i = t; i < 1024; i += 256) {
    int r = i >> 4, c4 = (i & 15) << 2;
    *(f32x4*)&ldsA[r][c4] = *(const f32x4*)&attn[(long)(b * 64 + r) * 64 + c4];
  }
  __syncthreads();
  const int cc0 = (t >> 4) << 1, dd0 = (t & 15) << 2;
  float acc[2][4] = {};
  for (int e = 0; e < 64; e += 4) {
    f32x4 wv2[2], av[4];
#pragma unroll
    for (int i = 0; i < 2; i++) wv2[i] = *(const f32x4*)&ldsW[cc0 + i][e];
#pragma unroll
    for (int p = 0; p < 4; p++) av[p] = *(const f32x4*)&ldsA[e + p][dd0];
#pragma unroll
    for (int i = 0; i < 2; i++)
#pragma unroll
      for (int p = 0; p < 4; p++) {
        float ww = wv2[i][p];
        acc[i][0] += ww * av[p][0]; acc[i][1] += ww * av[p][1];
        acc[i][2] += ww * av[p][2]; acc[i][3] += ww * av[p][3];
      }
  }
  const float g = gamma[0];
  const int s = dd0 >> 5, q = (dd0 & 31) >> 3, jj = dd0 & 7;
#pragma unroll
  for (int i = 0; i < 2; i++) {
    const int c = cb * 32 + cc0 + i;
    const int ct = c >> 4, cl = c & 15;
    U4 hv, lv;
#pragma unroll
    for (int j = 0; j < 4; j++) {
      float m = g * acc[i][j];
      unsigned short h = f2bfu(m);
      hv.a[j] = h;
      lv.a[j] = f2bfu(m - bfu2f(h));
    }
    long base = (((long)b * 32 + ct) * 2 + s) * 512 + (q * 16 + cl) * 8 + jj;
    *(u16x4*)&MpPhi[base] = hv.v;
    *(u16x4*)&MpPlo[base] = lv.v;
  }
}

// ---------------- K3: out = M'@V (split-bf16 MFMA) + gamma*b_o + x ----------------
// Grid (32 nt, 4 ct, 16 b), 256 thr = 4 waves. Tile 128c x 128n, K=64 (2 steps).
// V tile staged once in LDS (hi/lo, XOR-swizzled 16B slots -> <=2-way banks).
// A-frags: coalesced 1KB loads from packed Mp (L2-resident). 96 MFMA/wave.
__global__ __launch_bounds__(256, 4) void k3_out(
    const unsigned short* __restrict__ Vphi, const unsigned short* __restrict__ Vplo,
    const unsigned short* __restrict__ MpPhi, const unsigned short* __restrict__ MpPlo,
    const float* __restrict__ x, const float* __restrict__ bo,
    const float* __restrict__ gamma, float* __restrict__ out) {
  const int nt = blockIdx.x;   // 0..31
  const int ct = blockIdx.y;   // 0..3
  const int b  = blockIdx.z;
  const int t  = threadIdx.x;
  const int lane = t & 63;
  const int wid = t >> 6;      // 0..3
  const int wc = wid >> 1, wn = wid & 1;
  const int q4 = lane >> 4, l16 = lane & 15;

  __shared__ unsigned short ldsVhi[128][64];  // 16 KB
  __shared__ unsigned short ldsVlo[128][64];  // 16 KB

  // stage V tile: n in [nt*128, +128), all 64 d. slot ds^(n&7) swizzle.
  const unsigned short* Vh = Vphi + ((long)b * NSP + nt * 128) * 64;
  const unsigned short* Vl = Vplo + ((long)b * NSP + nt * 128) * 64;
#pragma unroll
  for (int p = 0; p < 4; p++) {
    int idx = p * 256 + t;          // 0..1023 = n*8 + ds
    int n = idx >> 3, ds = idx & 7;
    int slot = ds ^ (n & 7);
    *(u16x8*)&ldsVhi[n][slot * 8] = *(const u16x8*)&Vh[(long)idx * 8];
    *(u16x8*)&ldsVlo[n][slot * 8] = *(const u16x8*)&Vl[(long)idx * 8];
  }
  __syncthreads();

  f32x4 acc[4][4] = {};
#pragma unroll
  for (int s = 0; s < 2; s++) {
    F8 bhi[4], blo[4];
#pragma unroll
    for (int ni = 0; ni < 4; ni++) {
      const int n = wn * 64 + ni * 16 + l16;
      const int slot = (s * 4 + q4) ^ (n & 7);
      bhi[ni].us = *(const u16x8*)&ldsVhi[n][slot * 8];
      blo[ni].us = *(const u16x8*)&ldsVlo[n][slot * 8];
    }
#pragma unroll
    for (int i = 0; i < 4; i++) {
      const int ctg = ct * 8 + wc * 4 + i;      // c-tile 0..31
      const long base = (((long)b * 32 + ctg) * 2 + s) * 512 + (long)lane * 8;
      F8 Ahi, Alo;
      Ahi.us = *(const u16x8*)&MpPhi[base];
      Alo.us = *(const u16x8*)&MpPlo[base];
#pragma unroll
      for (int ni = 0; ni < 4; ni++) {
        acc[i][ni] = __builtin_amdgcn_mfma_f32_16x16x32_bf16(Ahi.bf, bhi[ni].bf, acc[i][ni], 0, 0, 0);
        acc[i][ni] = __builtin_amdgcn_mfma_f32_16x16x32_bf16(Ahi.bf, blo[ni].bf, acc[i][ni], 0, 0, 0);
        acc[i][ni] = __builtin_amdgcn_mfma_f32_16x16x32_bf16(Alo.bf, bhi[ni].bf, acc[i][ni], 0, 0, 0);
      }
    }
  }

  // epilogue: C/D col=lane&15 (n), row=(lane>>4)*4+r (c)
  const float g = gamma[0];
#pragma unroll
  for (int i = 0; i < 4; i++) {
    const int c4 = ct * 128 + wc * 64 + i * 16 + q4 * 4;
#pragma unroll
    for (int r = 0; r < 4; r++) {
      const int c = c4 + r;
      const float bb = g * bo[c];
#pragma unroll
      for (int ni = 0; ni < 4; ni++) {
        const int n = nt * 128 + wn * 64 + ni * 16 + l16;
        const long off = (long)(b * NC + c) * NSP + n;
        out[off] = acc[i][ni][r] + x[off] + bb;
      }
    }
  }
}

extern "C" void kernel_launch(void* const* d_in, const int* in_sizes, int n_in,
                              void* d_out, int out_size, void* d_ws, size_t ws_size,
                              hipStream_t stream) {
  const float* x   = (const float*)d_in[0];
  const float* wq  = (const float*)d_in[1];
  const float* bq  = (const float*)d_in[2];
  const float* wk  = (const float*)d_in[3];
  const float* bk  = (const float*)d_in[4];
  const float* wv  = (const float*)d_in[5];
  const float* bv  = (const float*)d_in[6];
  const float* wo  = (const float*)d_in[7];
  const float* bo  = (const float*)d_in[8];
  const float* gm  = (const float*)d_in[9];
  float* out = (float*)d_out;
  float* ws  = (float*)d_ws;

  // ws carve (floats)
  float* qkv  = ws;                                         // 128*4096*16 = 8,388,608
  float* part = ws + 8388608;                               // 16*16*4096  = 1,048,576
  float* attn = ws + 9437184;                               // 65,536
  unsigned short* MpPhi = (unsigned short*)(ws + 9502720);  // 524,288 u16 = 262,144 f
  unsigned short* MpPlo = (unsigned short*)(ws + 9764864);  // 262,144 f
  unsigned short* Vphi  = (unsigned short*)(ws + 10027008); // 4,194,304 u16 = 2,097,152 f
  unsigned short* Vplo  = (unsigned short*)(ws + 12124160); // 2,097,152 f
  unsigned short* WhiP  = (unsigned short*)(ws + 14221312); // 98,304 u16
  unsigned short* WloP  = (unsigned short*)(ws + 14270464); // 65,536 u16
  float* biasAll = ws + 14303232;                           // 192

  k0_wprep<<<384, 256, 0, stream>>>(wq, wk, wv, bq, bk, bv, WhiP, WloP, biasAll);
  k1_qkv<<<dim3(32, 16), 512, 0, stream>>>(x, WhiP, WloP, biasAll, qkv, Vphi, Vplo);
  k2a_logits<<<dim3(16, 16), 512, 0, stream>>>(qkv, part);
  k2b_softmax<<<dim3(64, 16), 64, 0, stream>>>(part, attn);
  k2c_mprime<<<dim3(16, 16), 256, 0, stream>>>(attn, wo, gm, MpPhi, MpPlo);
  k3_out<<<dim3(32, 4, 16), 256, 0, stream>>>(Vphi, Vplo, MpPhi, MpPlo, x, bo, gm, out);
}